// Round 2
// baseline (397.170 us; speedup 1.0000x reference)
//
#include <hip/hip_runtime.h>
#include <hip/hip_bf16.h>
#include <cstdint>
#include <cstddef>
#include <math.h>

#define D 256
#define TEMP_INV 2.0f       // 1 / TEMPERATURE, TEMPERATURE = 0.5
#define EPS_NORM 1e-8f

typedef __attribute__((ext_vector_type(8))) short bf16x8;
typedef __attribute__((ext_vector_type(4))) float f32x4;

// ---------------- kernel 1: normalize rows, write bf16 zn ----------------
// one wave per row; 64 lanes x float4 = 256 elements. Also zeros denom.
__global__ void __launch_bounds__(256) normalize_rows(
    const float* __restrict__ zi, const float* __restrict__ zj,
    __hip_bfloat16* __restrict__ zn, float* __restrict__ denom, int B) {
  int row = blockIdx.x * 4 + (threadIdx.x >> 6);
  int lane = threadIdx.x & 63;
  if (threadIdx.x < 4) denom[blockIdx.x * 4 + threadIdx.x] = 0.0f;
  const float* src = (row < B) ? (zi + (size_t)row * D)
                               : (zj + (size_t)(row - B) * D);
  float4 v = ((const float4*)src)[lane];
  float ss = v.x * v.x + v.y * v.y + v.z * v.z + v.w * v.w;
  for (int off = 32; off; off >>= 1) ss += __shfl_xor(ss, off);
  float rn = 1.0f / fmaxf(sqrtf(ss), EPS_NORM);
  union { ushort4 u; __hip_bfloat16 h[4]; } o;
  o.h[0] = __float2bfloat16(v.x * rn);
  o.h[1] = __float2bfloat16(v.y * rn);
  o.h[2] = __float2bfloat16(v.z * rn);
  o.h[3] = __float2bfloat16(v.w * rn);
  ((ushort4*)zn)[(size_t)row * (D / 4) + lane] = o.u;
}

// ---------------- kernel 2: fused sim GEMM + exp + masked row-sum --------
// 128x128 tile per block, 4 waves in 2x2, each wave 64x64 via 4x4 of
// 16x16x32 bf16 MFMA. VGPR-staged, XOR-swizzled LDS (conflict-free reads),
// register prefetch of next K-chunk overlaps L2 latency with MFMA.
__global__ void __launch_bounds__(256) ntxent_gemm(
    const __hip_bfloat16* __restrict__ zn,
    float* __restrict__ denom, float* __restrict__ pos, int B) {
  __shared__ __align__(16) __hip_bfloat16 Ash[128 * 64];
  __shared__ __align__(16) __hip_bfloat16 Bsh[128 * 64];

  const int tid = threadIdx.x;
  const int wid = tid >> 6;
  const int lane = tid & 63;
  const int wy = wid >> 1, wx = wid & 1;
  const int bm = blockIdx.y * 128;
  const int bn = blockIdx.x * 128;

  f32x4 acc[4][4] = {};

  // staging geometry: wave stages its 32 rows (A and B) per 64-wide K chunk.
  // lane -> row (lane>>3), 16B chunk (lane&7). LDS chunk swizzled by row&7.
  const int lr = lane >> 3;       // row within 8-row group == row&7
  const int lc = lane & 7;        // 16B chunk index
  const int swz = lc ^ lr;        // swizzled chunk
  const int wrow0 = wid * 32;

  const int frow = lane & 15;     // m/n index within 16x16 frag (input side)
  const int quad = lane >> 4;     // 0..3
  const int f7 = frow & 7;

  float4 ra[4], rb[4];
#pragma unroll
  for (int s = 0; s < 4; ++s) {
    int r = wrow0 + s * 8 + lr;
    ra[s] = *(const float4*)(zn + (size_t)(bm + r) * D + lc * 8);
    rb[s] = *(const float4*)(zn + (size_t)(bn + r) * D + lc * 8);
  }

#pragma unroll
  for (int k0i = 0; k0i < 4; ++k0i) {
    float4 na[4], nb[4];
    if (k0i < 3) {
      const int k0n = (k0i + 1) * 64;
#pragma unroll
      for (int s = 0; s < 4; ++s) {
        int r = wrow0 + s * 8 + lr;
        na[s] = *(const float4*)(zn + (size_t)(bm + r) * D + k0n + lc * 8);
        nb[s] = *(const float4*)(zn + (size_t)(bn + r) * D + k0n + lc * 8);
      }
    }
    __syncthreads();  // prior iter's LDS reads complete
#pragma unroll
    for (int s = 0; s < 4; ++s) {
      int r = wrow0 + s * 8 + lr;
      *(float4*)&Ash[r * 64 + swz * 8] = ra[s];
      *(float4*)&Bsh[r * 64 + swz * 8] = rb[s];
    }
    __syncthreads();
#pragma unroll
    for (int kk = 0; kk < 2; ++kk) {
      bf16x8 a[4], b[4];
#pragma unroll
      for (int i = 0; i < 4; ++i)
        a[i] = *(const bf16x8*)
            &Ash[(wy * 64 + i * 16 + frow) * 64 + ((kk * 4 + quad) ^ f7) * 8];
#pragma unroll
      for (int j = 0; j < 4; ++j)
        b[j] = *(const bf16x8*)
            &Bsh[(wx * 64 + j * 16 + frow) * 64 + ((kk * 4 + quad) ^ f7) * 8];
#pragma unroll
      for (int i = 0; i < 4; ++i)
#pragma unroll
        for (int j = 0; j < 4; ++j)
          acc[i][j] =
              __builtin_amdgcn_mfma_f32_16x16x32_bf16(a[i], b[j], acc[i][j], 0, 0, 0);
    }
    if (k0i < 3) {
#pragma unroll
      for (int s = 0; s < 4; ++s) { ra[s] = na[s]; rb[s] = nb[s]; }
    }
  }

  // epilogue: C/D layout col = lane&15, row = quad*4 + reg
  const int colq = lane & 15;
#pragma unroll
  for (int i = 0; i < 4; ++i) {
#pragma unroll
    for (int r = 0; r < 4; ++r) {
      int row = bm + wy * 64 + i * 16 + quad * 4 + r;
      float rs = 0.0f;
#pragma unroll
      for (int j = 0; j < 4; ++j) {
        int col = bn + wx * 64 + j * 16 + colq;
        float v = acc[i][j][r];
        if (col != row) rs += __expf(v * TEMP_INV);
        if (col == row + B || col + B == row) pos[row] = v;  // exactly one writer
      }
      rs += __shfl_xor(rs, 1);
      rs += __shfl_xor(rs, 2);
      rs += __shfl_xor(rs, 4);
      rs += __shfl_xor(rs, 8);
      if (colq == 0) atomicAdd(&denom[row], rs);
    }
  }
}

// ---------------- kernel 3: finalize loss scalar -------------------------
__global__ void __launch_bounds__(256) finalize(
    const float* __restrict__ denom, const float* __restrict__ pos,
    float* __restrict__ out, int N) {
  __shared__ float red[256];
  float s = 0.0f;
  for (int i = threadIdx.x; i < N; i += 256)
    s += __logf(denom[i]) - pos[i] * TEMP_INV;
  red[threadIdx.x] = s;
  __syncthreads();
  for (int off = 128; off; off >>= 1) {
    if ((int)threadIdx.x < off) red[threadIdx.x] += red[threadIdx.x + off];
    __syncthreads();
  }
  if (threadIdx.x == 0) out[0] = red[0] / (float)N;
}

extern "C" void kernel_launch(void* const* d_in, const int* in_sizes, int n_in,
                              void* d_out, int out_size, void* d_ws, size_t ws_size,
                              hipStream_t stream) {
  const float* zi = (const float*)d_in[0];
  const float* zj = (const float*)d_in[1];
  const int B = in_sizes[0] / D;  // 4096
  const int N = 2 * B;            // 8192

  __hip_bfloat16* zn = (__hip_bfloat16*)d_ws;
  float* denom = (float*)((char*)d_ws + (size_t)N * D * sizeof(__hip_bfloat16));
  float* pos = denom + N;

  normalize_rows<<<N / 4, 256, 0, stream>>>(zi, zj, zn, denom, B);
  dim3 grid(N / 128, N / 128);
  ntxent_gemm<<<grid, 256, 0, stream>>>(zn, denom, pos, B);
  finalize<<<1, 256, 0, stream>>>(denom, pos, (float*)d_out, N);
}

// Round 3
// 166.346 us; speedup vs baseline: 2.3876x; 2.3876x over previous
//
#include <hip/hip_runtime.h>
#include <hip/hip_bf16.h>
#include <cstdint>
#include <cstddef>
#include <math.h>

#define D 256
#define TEMP_INV 2.0f       // 1 / TEMPERATURE, TEMPERATURE = 0.5
#define EPS_NORM 1e-8f

typedef __attribute__((ext_vector_type(8))) short bf16x8;
typedef __attribute__((ext_vector_type(4))) float f32x4;

// ---------------- kernel 1: normalize rows, write bf16 zn ----------------
// one wave per row; 64 lanes x float4 = 256 elements. Also zeros denom.
__global__ void __launch_bounds__(256) normalize_rows(
    const float* __restrict__ zi, const float* __restrict__ zj,
    __hip_bfloat16* __restrict__ zn, float* __restrict__ denom, int B) {
  int row = blockIdx.x * 4 + (threadIdx.x >> 6);
  int lane = threadIdx.x & 63;
  if (threadIdx.x < 4) denom[blockIdx.x * 4 + threadIdx.x] = 0.0f;
  const float* src = (row < B) ? (zi + (size_t)row * D)
                               : (zj + (size_t)(row - B) * D);
  float4 v = ((const float4*)src)[lane];
  float ss = v.x * v.x + v.y * v.y + v.z * v.z + v.w * v.w;
  for (int off = 32; off; off >>= 1) ss += __shfl_xor(ss, off);
  float rn = 1.0f / fmaxf(sqrtf(ss), EPS_NORM);
  union { ushort4 u; __hip_bfloat16 h[4]; } o;
  o.h[0] = __float2bfloat16(v.x * rn);
  o.h[1] = __float2bfloat16(v.y * rn);
  o.h[2] = __float2bfloat16(v.z * rn);
  o.h[3] = __float2bfloat16(v.w * rn);
  ((ushort4*)zn)[(size_t)row * (D / 4) + lane] = o.u;
}

// ---------------- kernel 2: fused sim GEMM + exp + masked row-sum --------
// 128x128 tile per block, 4 waves in 2x2, each wave 64x64 via 4x4 of
// 16x16x32 bf16 MFMA. global_load_lds staging (no VGPR pressure) with the
// XOR bank-swizzle applied on the GLOBAL SOURCE address: LDS(r,c') holds
// global chunk c'^(r&7), so fragment ds_read_b128s are conflict-free.
__device__ __forceinline__ void load_lds_16B(const __hip_bfloat16* g,
                                             __hip_bfloat16* l) {
  __builtin_amdgcn_global_load_lds(
      (const __attribute__((address_space(1))) void*)g,
      (__attribute__((address_space(3))) void*)l, 16, 0, 0);
}

__global__ void __launch_bounds__(256) ntxent_gemm(
    const __hip_bfloat16* __restrict__ zn,
    float* __restrict__ denom, float* __restrict__ pos, int B) {
  __shared__ __align__(16) __hip_bfloat16 Ash[128 * 64];
  __shared__ __align__(16) __hip_bfloat16 Bsh[128 * 64];

  const int tid = threadIdx.x;
  const int wid = tid >> 6;
  const int lane = tid & 63;
  const int wy = wid >> 1, wx = wid & 1;
  const int bm = blockIdx.y * 128;
  const int bn = blockIdx.x * 128;

  f32x4 acc[4][4] = {};

  // staging: wave stages its 32 rows (A and B) per 64-wide K chunk in 4
  // wave-ops of 1KB. lane -> row (lane>>3), global 16B chunk (lc ^ lr).
  const int lr = lane >> 3;
  const int lc = lane & 7;
  const int srcchunk = (lc ^ lr) * 8;   // element offset of swizzled chunk
  const int wrow0 = wid * 32;

  const int frow = lane & 15;     // m/n index within 16x16 frag (input side)
  const int quad = lane >> 4;     // 0..3
  const int f7 = frow & 7;

  for (int k0 = 0; k0 < D; k0 += 64) {
#pragma unroll
    for (int s = 0; s < 4; ++s) {
      int r = wrow0 + s * 8 + lr;
      const __hip_bfloat16* ga = zn + (size_t)(bm + r) * D + k0 + srcchunk;
      const __hip_bfloat16* gb = zn + (size_t)(bn + r) * D + k0 + srcchunk;
      // wave-uniform LDS base; HW adds lane*16B
      load_lds_16B(ga, &Ash[(wrow0 + s * 8) * 64]);
      load_lds_16B(gb, &Bsh[(wrow0 + s * 8) * 64]);
    }
    __syncthreads();
#pragma unroll
    for (int kk = 0; kk < 2; ++kk) {
      bf16x8 a[4], b[4];
#pragma unroll
      for (int i = 0; i < 4; ++i)
        a[i] = *(const bf16x8*)
            &Ash[(wy * 64 + i * 16 + frow) * 64 + ((kk * 4 + quad) ^ f7) * 8];
#pragma unroll
      for (int j = 0; j < 4; ++j)
        b[j] = *(const bf16x8*)
            &Bsh[(wx * 64 + j * 16 + frow) * 64 + ((kk * 4 + quad) ^ f7) * 8];
#pragma unroll
      for (int i = 0; i < 4; ++i)
#pragma unroll
        for (int j = 0; j < 4; ++j)
          acc[i][j] =
              __builtin_amdgcn_mfma_f32_16x16x32_bf16(a[i], b[j], acc[i][j], 0, 0, 0);
    }
    __syncthreads();
  }

  // epilogue: C/D layout col = lane&15, row = quad*4 + reg
  const int colq = lane & 15;
#pragma unroll
  for (int i = 0; i < 4; ++i) {
#pragma unroll
    for (int r = 0; r < 4; ++r) {
      int row = bm + wy * 64 + i * 16 + quad * 4 + r;
      float rs = 0.0f;
#pragma unroll
      for (int j = 0; j < 4; ++j) {
        int col = bn + wx * 64 + j * 16 + colq;
        float v = acc[i][j][r];
        if (col != row) rs += __expf(v * TEMP_INV);
        if (col == row + B || col + B == row) pos[row] = v;  // exactly one writer
      }
      rs += __shfl_xor(rs, 1);
      rs += __shfl_xor(rs, 2);
      rs += __shfl_xor(rs, 4);
      rs += __shfl_xor(rs, 8);
      if (colq == 0) atomicAdd(&denom[row], rs);
    }
  }
}

// ---------------- kernel 3: finalize loss scalar -------------------------
__global__ void __launch_bounds__(256) finalize(
    const float* __restrict__ denom, const float* __restrict__ pos,
    float* __restrict__ out, int N) {
  __shared__ float red[256];
  float s = 0.0f;
  for (int i = threadIdx.x; i < N; i += 256)
    s += __logf(denom[i]) - pos[i] * TEMP_INV;
  red[threadIdx.x] = s;
  __syncthreads();
  for (int off = 128; off; off >>= 1) {
    if ((int)threadIdx.x < off) red[threadIdx.x] += red[threadIdx.x + off];
    __syncthreads();
  }
  if (threadIdx.x == 0) out[0] = red[0] / (float)N;
}

extern "C" void kernel_launch(void* const* d_in, const int* in_sizes, int n_in,
                              void* d_out, int out_size, void* d_ws, size_t ws_size,
                              hipStream_t stream) {
  const float* zi = (const float*)d_in[0];
  const float* zj = (const float*)d_in[1];
  const int B = in_sizes[0] / D;  // 4096
  const int N = 2 * B;            // 8192

  __hip_bfloat16* zn = (__hip_bfloat16*)d_ws;
  float* denom = (float*)((char*)d_ws + (size_t)N * D * sizeof(__hip_bfloat16));
  float* pos = denom + N;

  normalize_rows<<<N / 4, 256, 0, stream>>>(zi, zj, zn, denom, B);
  dim3 grid(N / 128, N / 128);
  ntxent_gemm<<<grid, 256, 0, stream>>>(zn, denom, pos, B);
  finalize<<<1, 256, 0, stream>>>(denom, pos, (float*)d_out, N);
}

// Round 4
// 130.033 us; speedup vs baseline: 3.0544x; 1.2793x over previous
//
#include <hip/hip_runtime.h>
#include <hip/hip_bf16.h>
#include <cstdint>
#include <cstddef>
#include <math.h>

#define D 256
#define TEMP_INV 2.0f       // 1 / TEMPERATURE, TEMPERATURE = 0.5
#define EPS_NORM 1e-8f

typedef __attribute__((ext_vector_type(8))) short bf16x8;
typedef __attribute__((ext_vector_type(4))) float f32x4;

// ---------------- kernel 1: normalize rows, write bf16 zn ----------------
// one wave per row; 64 lanes x float4 = 256 elements. Also zeros denom.
__global__ void __launch_bounds__(256) normalize_rows(
    const float* __restrict__ zi, const float* __restrict__ zj,
    __hip_bfloat16* __restrict__ zn, float* __restrict__ denom, int B) {
  int row = blockIdx.x * 4 + (threadIdx.x >> 6);
  int lane = threadIdx.x & 63;
  if (threadIdx.x < 4) denom[blockIdx.x * 4 + threadIdx.x] = 0.0f;
  const float* src = (row < B) ? (zi + (size_t)row * D)
                               : (zj + (size_t)(row - B) * D);
  float4 v = ((const float4*)src)[lane];
  float ss = v.x * v.x + v.y * v.y + v.z * v.z + v.w * v.w;
  for (int off = 32; off; off >>= 1) ss += __shfl_xor(ss, off);
  float rn = 1.0f / fmaxf(sqrtf(ss), EPS_NORM);
  union { ushort4 u; __hip_bfloat16 h[4]; } o;
  o.h[0] = __float2bfloat16(v.x * rn);
  o.h[1] = __float2bfloat16(v.y * rn);
  o.h[2] = __float2bfloat16(v.z * rn);
  o.h[3] = __float2bfloat16(v.w * rn);
  ((ushort4*)zn)[(size_t)row * (D / 4) + lane] = o.u;
}

// ---------------- kernel 2: fused sim GEMM + exp + masked row/col sums ---
// SYMMETRIC: only upper-triangular 128x128 blocks (by<=bx). Off-diagonal
// blocks emit row sums (rs) AND column sums (cs) so each sim entry is
// computed once. 4 waves in 2x2, each wave 64x64 via 4x4 of 16x16x32 MFMA.
// global_load_lds staging with XOR bank-swizzle on the global source addr.
__device__ __forceinline__ void load_lds_16B(const __hip_bfloat16* g,
                                             __hip_bfloat16* l) {
  __builtin_amdgcn_global_load_lds(
      (const __attribute__((address_space(1))) void*)g,
      (__attribute__((address_space(3))) void*)l, 16, 0, 0);
}

__global__ void __launch_bounds__(256) ntxent_gemm(
    const __hip_bfloat16* __restrict__ zn,
    float* __restrict__ denom, float* __restrict__ pos, int B) {
  __shared__ __align__(16) __hip_bfloat16 Ash[128 * 64];
  __shared__ __align__(16) __hip_bfloat16 Bsh[128 * 64];

  // ---- decode linear block index -> upper-triangular (by, bx), by<=bx ----
  const int Nb = (2 * B) / 128;  // 64
  {
  }
  int t = blockIdx.x;
  float fb = (2.0f * Nb + 1.0f -
              sqrtf((float)((2 * Nb + 1) * (2 * Nb + 1) - 8 * t))) * 0.5f;
  int by = (int)fb;
  while ((by + 1) * Nb - ((by + 1) * by) / 2 <= t) ++by;
  while (by * Nb - (by * (by - 1)) / 2 > t) --by;
  const int bx = by + (t - (by * Nb - (by * (by - 1)) / 2));

  const int bm = by * 128;
  const int bn = bx * 128;
  const bool isDiag = (by == bx);
  const bool isPos = (bx == by + B / 128);

  const int tid = threadIdx.x;
  const int wid = tid >> 6;
  const int lane = tid & 63;
  const int wy = wid >> 1, wx = wid & 1;

  f32x4 acc[4][4] = {};

  // staging: wave stages its 32 rows (A and B) per 64-wide K chunk in 4
  // wave-ops of 1KB. lane -> row (lane>>3), global 16B chunk (lc ^ lr).
  const int lr = lane >> 3;
  const int lc = lane & 7;
  const int srcchunk = (lc ^ lr) * 8;   // element offset of swizzled chunk
  const int wrow0 = wid * 32;

  const int frow = lane & 15;     // m/n index within 16x16 frag (input side)
  const int quad = lane >> 4;     // 0..3
  const int f7 = frow & 7;

  for (int k0 = 0; k0 < D; k0 += 64) {
#pragma unroll
    for (int s = 0; s < 4; ++s) {
      int r = wrow0 + s * 8 + lr;
      const __hip_bfloat16* ga = zn + (size_t)(bm + r) * D + k0 + srcchunk;
      const __hip_bfloat16* gb = zn + (size_t)(bn + r) * D + k0 + srcchunk;
      // wave-uniform LDS base; HW adds lane*16B
      load_lds_16B(ga, &Ash[(wrow0 + s * 8) * 64]);
      load_lds_16B(gb, &Bsh[(wrow0 + s * 8) * 64]);
    }
    __syncthreads();
#pragma unroll
    for (int kk = 0; kk < 2; ++kk) {
      bf16x8 a[4], b[4];
#pragma unroll
      for (int i = 0; i < 4; ++i)
        a[i] = *(const bf16x8*)
            &Ash[(wy * 64 + i * 16 + frow) * 64 + ((kk * 4 + quad) ^ f7) * 8];
#pragma unroll
      for (int j = 0; j < 4; ++j)
        b[j] = *(const bf16x8*)
            &Bsh[(wx * 64 + j * 16 + frow) * 64 + ((kk * 4 + quad) ^ f7) * 8];
#pragma unroll
      for (int i = 0; i < 4; ++i)
#pragma unroll
        for (int j = 0; j < 4; ++j)
          acc[i][j] =
              __builtin_amdgcn_mfma_f32_16x16x32_bf16(a[i], b[j], acc[i][j], 0, 0, 0);
    }
    __syncthreads();
  }

  // epilogue: C/D layout col = lane&15, row = quad*4 + reg
  const int colq = lane & 15;
  float cs[4] = {0.0f, 0.0f, 0.0f, 0.0f};
#pragma unroll
  for (int i = 0; i < 4; ++i) {
#pragma unroll
    for (int r = 0; r < 4; ++r) {
      int row = bm + wy * 64 + i * 16 + quad * 4 + r;
      float rs = 0.0f;
#pragma unroll
      for (int j = 0; j < 4; ++j) {
        int col = bn + wx * 64 + j * 16 + colq;
        float v = acc[i][j][r];
        float e = __expf(v * TEMP_INV);
        e = (isDiag && col == row) ? 0.0f : e;
        rs += e;
        cs[j] += e;
        if (isPos && col == row + B) { pos[row] = v; pos[col] = v; }
      }
      rs += __shfl_xor(rs, 1);
      rs += __shfl_xor(rs, 2);
      rs += __shfl_xor(rs, 4);
      rs += __shfl_xor(rs, 8);
      if (colq == 0) atomicAdd(&denom[row], rs);
    }
  }
  if (!isDiag) {
#pragma unroll
    for (int j = 0; j < 4; ++j) {
      float c = cs[j];
      c += __shfl_xor(c, 16);
      c += __shfl_xor(c, 32);
      if (quad == 0) atomicAdd(&denom[bn + wx * 64 + j * 16 + colq], c);
    }
  }
}

// ---------------- kernel 3: finalize loss scalar -------------------------
__global__ void __launch_bounds__(256) finalize(
    const float* __restrict__ denom, const float* __restrict__ pos,
    float* __restrict__ out, int N) {
  __shared__ float red[256];
  float s = 0.0f;
  for (int i = threadIdx.x; i < N; i += 256)
    s += __logf(denom[i]) - pos[i] * TEMP_INV;
  red[threadIdx.x] = s;
  __syncthreads();
  for (int off = 128; off; off >>= 1) {
    if ((int)threadIdx.x < off) red[threadIdx.x] += red[threadIdx.x + off];
    __syncthreads();
  }
  if (threadIdx.x == 0) out[0] = red[0] / (float)N;
}

extern "C" void kernel_launch(void* const* d_in, const int* in_sizes, int n_in,
                              void* d_out, int out_size, void* d_ws, size_t ws_size,
                              hipStream_t stream) {
  const float* zi = (const float*)d_in[0];
  const float* zj = (const float*)d_in[1];
  const int B = in_sizes[0] / D;  // 4096
  const int N = 2 * B;            // 8192

  __hip_bfloat16* zn = (__hip_bfloat16*)d_ws;
  float* denom = (float*)((char*)d_ws + (size_t)N * D * sizeof(__hip_bfloat16));
  float* pos = denom + N;

  normalize_rows<<<N / 4, 256, 0, stream>>>(zi, zj, zn, denom, B);
  const int Nb = N / 128;                 // 64
  const int nblocks = Nb * (Nb + 1) / 2;  // 2080
  ntxent_gemm<<<nblocks, 256, 0, stream>>>(zn, denom, pos, B);
  finalize<<<1, 256, 0, stream>>>(denom, pos, (float*)d_out, N);
}

// Round 5
// 122.794 us; speedup vs baseline: 3.2345x; 1.0590x over previous
//
#include <hip/hip_runtime.h>
#include <hip/hip_bf16.h>
#include <cstdint>
#include <cstddef>
#include <math.h>

#define D 256
#define TEMP_INV 2.0f       // 1 / TEMPERATURE, TEMPERATURE = 0.5
#define EPS_NORM 1e-8f
#define NTILES 2080         // 64*65/2 upper-triangular 128x128 tiles
#define GRID 512            // 2 blocks/CU (LDS 64KB -> exactly 2 resident)

typedef __attribute__((ext_vector_type(8))) short bf16x8;
typedef __attribute__((ext_vector_type(4))) float f32x4;

// ---------------- kernel 1: normalize rows, write bf16 zn ----------------
__global__ void __launch_bounds__(256) normalize_rows(
    const float* __restrict__ zi, const float* __restrict__ zj,
    __hip_bfloat16* __restrict__ zn, float* __restrict__ denom, int B) {
  int row = blockIdx.x * 4 + (threadIdx.x >> 6);
  int lane = threadIdx.x & 63;
  if (threadIdx.x < 4) denom[blockIdx.x * 4 + threadIdx.x] = 0.0f;
  const float* src = (row < B) ? (zi + (size_t)row * D)
                               : (zj + (size_t)(row - B) * D);
  float4 v = ((const float4*)src)[lane];
  float ss = v.x * v.x + v.y * v.y + v.z * v.z + v.w * v.w;
  for (int off = 32; off; off >>= 1) ss += __shfl_xor(ss, off);
  float rn = 1.0f / fmaxf(sqrtf(ss), EPS_NORM);
  union { ushort4 u; __hip_bfloat16 h[4]; } o;
  o.h[0] = __float2bfloat16(v.x * rn);
  o.h[1] = __float2bfloat16(v.y * rn);
  o.h[2] = __float2bfloat16(v.z * rn);
  o.h[3] = __float2bfloat16(v.w * rn);
  ((ushort4*)zn)[(size_t)row * (D / 4) + lane] = o.u;
}

// ---------------- kernel 2: persistent fused sim GEMM --------------------
// Upper-triangular 128x128 tiles; BK=128 (2 K-steps); grid=512 persistent
// blocks each walking ~4 tiles; next tile's stage issued before current
// epilogue so L2 drain overlaps exp/atomic latency. XOR swizzle on global
// source address keeps all ds_read_b128 conflict-free.
__device__ __forceinline__ void load_lds_16B(const __hip_bfloat16* g,
                                             __hip_bfloat16* l) {
  __builtin_amdgcn_global_load_lds(
      (const __attribute__((address_space(1))) void*)g,
      (__attribute__((address_space(3))) void*)l, 16, 0, 0);
}

__device__ __forceinline__ void decode_tile(int t, int Nb, int& by, int& bx) {
  float fb = (2.0f * Nb + 1.0f -
              sqrtf((float)((2 * Nb + 1) * (2 * Nb + 1) - 8 * t))) * 0.5f;
  int y = (int)fb;
  while ((y + 1) * Nb - ((y + 1) * y) / 2 <= t) ++y;
  while (y * Nb - (y * (y - 1)) / 2 > t) --y;
  by = y;
  bx = y + (t - (y * Nb - (y * (y - 1)) / 2));
}

// stage rows [wrow0, wrow0+32) of A and B for K-slab [k0, k0+128)
// LDS(r, c') holds global 16B chunk c'^(r&7): conflict-free on read.
__device__ __forceinline__ void stage_tile(
    const __hip_bfloat16* __restrict__ zn,
    __hip_bfloat16* Ash, __hip_bfloat16* Bsh,
    int bm, int bn, int k0, int wrow0, int lane) {
  const int lr4 = lane >> 4;   // 0..3: row within 4-row group
  const int lc16 = lane & 15;  // 16B chunk slot in LDS
#pragma unroll
  for (int s = 0; s < 8; ++s) {
    int r = wrow0 + s * 4 + lr4;
    int chunk = lc16 ^ (r & 7);
    const __hip_bfloat16* ga = zn + (size_t)(bm + r) * D + k0 + chunk * 8;
    const __hip_bfloat16* gb = zn + (size_t)(bn + r) * D + k0 + chunk * 8;
    // wave-uniform LDS base; HW adds lane*16B (4 rows x 16 chunks)
    load_lds_16B(ga, &Ash[(wrow0 + s * 4) * 128]);
    load_lds_16B(gb, &Bsh[(wrow0 + s * 4) * 128]);
  }
}

__device__ __forceinline__ void compute_k128(
    const __hip_bfloat16* Ash, const __hip_bfloat16* Bsh,
    f32x4 acc[4][4], int wy, int wx, int frow, int quad) {
  const int f7 = frow & 7;
#pragma unroll
  for (int kk = 0; kk < 4; ++kk) {
    bf16x8 a[4], b[4];
#pragma unroll
    for (int i = 0; i < 4; ++i)
      a[i] = *(const bf16x8*)
          &Ash[(wy * 64 + i * 16 + frow) * 128 + (((kk * 4 + quad) ^ f7)) * 8];
#pragma unroll
    for (int j = 0; j < 4; ++j)
      b[j] = *(const bf16x8*)
          &Bsh[(wx * 64 + j * 16 + frow) * 128 + (((kk * 4 + quad) ^ f7)) * 8];
#pragma unroll
    for (int i = 0; i < 4; ++i)
#pragma unroll
      for (int j = 0; j < 4; ++j)
        acc[i][j] =
            __builtin_amdgcn_mfma_f32_16x16x32_bf16(a[i], b[j], acc[i][j], 0, 0, 0);
  }
}

__global__ void __launch_bounds__(256) ntxent_gemm(
    const __hip_bfloat16* __restrict__ zn,
    float* __restrict__ denom, float* __restrict__ pos, int B) {
  __shared__ __align__(16) __hip_bfloat16 Ash[128 * 128];  // 32 KB
  __shared__ __align__(16) __hip_bfloat16 Bsh[128 * 128];  // 32 KB

  const int Nb = (2 * B) / 128;  // 64
  const int tid = threadIdx.x;
  const int wid = tid >> 6;
  const int lane = tid & 63;
  const int wy = wid >> 1, wx = wid & 1;
  const int wrow0 = wid * 32;
  const int frow = lane & 15;
  const int quad = lane >> 4;
  const int colq = lane & 15;

  int t = blockIdx.x;
  int by, bx;
  decode_tile(t, Nb, by, bx);
  int bm = by * 128, bn = bx * 128;
  stage_tile(zn, Ash, Bsh, bm, bn, 0, wrow0, lane);

  while (true) {
    f32x4 acc[4][4] = {};
    __syncthreads();  // drain stage(k=0) + all waves arrive
    compute_k128(Ash, Bsh, acc, wy, wx, frow, quad);
    __syncthreads();  // all LDS reads done
    stage_tile(zn, Ash, Bsh, bm, bn, 128, wrow0, lane);
    __syncthreads();  // drain stage(k=128)
    compute_k128(Ash, Bsh, acc, wy, wx, frow, quad);
    __syncthreads();  // all LDS reads done

    // prefetch next tile's first K-slab; drain overlaps epilogue below
    int nt = t + GRID;
    bool more = (nt < NTILES);
    int nbm = 0, nbn = 0;
    if (more) {
      int nby, nbx;
      decode_tile(nt, Nb, nby, nbx);
      nbm = nby * 128;
      nbn = nbx * 128;
      stage_tile(zn, Ash, Bsh, nbm, nbn, 0, wrow0, lane);
    }

    // epilogue for tile (bm, bn): C/D layout col = lane&15, row = quad*4+reg
    const bool isDiag = (bm == bn);
    const bool isPos = (bn == bm + B);
    float cs[4] = {0.0f, 0.0f, 0.0f, 0.0f};
#pragma unroll
    for (int i = 0; i < 4; ++i) {
#pragma unroll
      for (int r = 0; r < 4; ++r) {
        int row = bm + wy * 64 + i * 16 + quad * 4 + r;
        float rs = 0.0f;
#pragma unroll
        for (int j = 0; j < 4; ++j) {
          int col = bn + wx * 64 + j * 16 + colq;
          float v = acc[i][j][r];
          float e = __expf(v * TEMP_INV);
          e = (isDiag && col == row) ? 0.0f : e;
          rs += e;
          cs[j] += e;
          if (isPos && col == row + B) { pos[row] = v; pos[col] = v; }
        }
        rs += __shfl_xor(rs, 1);
        rs += __shfl_xor(rs, 2);
        rs += __shfl_xor(rs, 4);
        rs += __shfl_xor(rs, 8);
        if (colq == 0) atomicAdd(&denom[row], rs);
      }
    }
    if (!isDiag) {
#pragma unroll
      for (int j = 0; j < 4; ++j) {
        float c = cs[j];
        c += __shfl_xor(c, 16);
        c += __shfl_xor(c, 32);
        if (quad == 0) atomicAdd(&denom[bn + wx * 64 + j * 16 + colq], c);
      }
    }
    if (!more) break;
    t = nt;
    bm = nbm;
    bn = nbn;
  }
}

// ---------------- kernel 3: finalize loss scalar -------------------------
__global__ void __launch_bounds__(1024) finalize(
    const float* __restrict__ denom, const float* __restrict__ pos,
    float* __restrict__ out, int N) {
  __shared__ float red[16];
  const int tid = threadIdx.x;
  float s = 0.0f;
  for (int i = tid; i < N / 4; i += 1024) {
    float4 d = ((const float4*)denom)[i];
    float4 p = ((const float4*)pos)[i];
    s += __logf(d.x) - p.x * TEMP_INV;
    s += __logf(d.y) - p.y * TEMP_INV;
    s += __logf(d.z) - p.z * TEMP_INV;
    s += __logf(d.w) - p.w * TEMP_INV;
  }
  for (int off = 32; off; off >>= 1) s += __shfl_xor(s, off);
  if ((tid & 63) == 0) red[tid >> 6] = s;
  __syncthreads();
  if (tid < 16) {
    s = red[tid];
    s += __shfl_xor(s, 1);
    s += __shfl_xor(s, 2);
    s += __shfl_xor(s, 4);
    s += __shfl_xor(s, 8);
    if (tid == 0) out[0] = s / (float)N;
  }
}

extern "C" void kernel_launch(void* const* d_in, const int* in_sizes, int n_in,
                              void* d_out, int out_size, void* d_ws, size_t ws_size,
                              hipStream_t stream) {
  const float* zi = (const float*)d_in[0];
  const float* zj = (const float*)d_in[1];
  const int B = in_sizes[0] / D;  // 4096
  const int N = 2 * B;            // 8192

  __hip_bfloat16* zn = (__hip_bfloat16*)d_ws;
  float* denom = (float*)((char*)d_ws + (size_t)N * D * sizeof(__hip_bfloat16));
  float* pos = denom + N;

  normalize_rows<<<N / 4, 256, 0, stream>>>(zi, zj, zn, denom, B);
  ntxent_gemm<<<GRID, 256, 0, stream>>>(zn, denom, pos, B);
  finalize<<<1, 1024, 0, stream>>>(denom, pos, (float*)d_out, N);
}